// Round 6
// baseline (820.324 us; speedup 1.0000x reference)
//
#include <hip/hip_runtime.h>

// RGCN featureless: N=100000, S=50, B=30, OUT=16, E=20000.
// Reference quirk: V2 row index k = r*N + dst decodes NODE-major:
//   node' = k/50, rel' = k%50.  out[src] += val * V2[k][:], then ReLU.
//
// Rounds 2-4 evidence: duration invariant (273-278us) across atomics/no-atomics,
// WRITE 250->94MB, occupancy 88->33% -- the wall is the 30M random 64B gather
// line-requests (30/edge, one per basis; ~5.6 cyc/line/CU, MSHR-latency bound).
// Round 5: materialize V2 chunk-by-chunk (streaming build, wave-coherent W
// reads), then gather ONE line per edge. 30M -> 1M gather lines.
constexpr int S_REL = 50;
constexpr int B_BASES = 30;
constexpr int OUT_DIM = 16;

// ---------------- round-5 pipeline ----------------

// V2c[idx][o] = sum_b Wcomp[(kBase+idx)%50, b] * W[b][(kBase+idx)/50][o]
// Sequential idx -> waves share W lines (16 consecutive k = 1-2 node' values),
// streaming read of W, fully coalesced 64B-row writes of V2c.
__global__ __launch_bounds__(256) void build_v2_kernel(
    const float* __restrict__ W, const float* __restrict__ Wcomp,
    float* __restrict__ V2c, int kBase, int rows, int N) {
    __shared__ float wc[S_REL * B_BASES];  // 6 KB
    for (int i = threadIdx.x; i < S_REL * B_BASES; i += blockDim.x)
        wc[i] = Wcomp[i];
    __syncthreads();

    int t = blockIdx.x * blockDim.x + threadIdx.x;
    int idx = t >> 2;
    int o4 = (t & 3) * 4;
    if (idx >= rows) return;

    int k = kBase + idx;
    int node = k / S_REL;              // const divisor -> magic mul
    int rel = k - node * S_REL;

    const float* wp = W + (size_t)node * OUT_DIM + o4;
    const size_t bstride = (size_t)N * OUT_DIM;
    const float* c = wc + rel * B_BASES;

    float4 acc = make_float4(0.f, 0.f, 0.f, 0.f);
#pragma unroll
    for (int b = 0; b < B_BASES; ++b) {
        float4 w4 = *reinterpret_cast<const float4*>(wp + (size_t)b * bstride);
        acc.x = fmaf(c[b], w4.x, acc.x);
        acc.y = fmaf(c[b], w4.y, acc.y);
        acc.z = fmaf(c[b], w4.z, acc.z);
        acc.w = fmaf(c[b], w4.w, acc.w);
    }
    *reinterpret_cast<float4*>(V2c + (size_t)idx * OUT_DIM + o4) = acc;
}

// 16 lanes per edge (lane = output col): ONE 64B gather line per edge
// (16 consecutive floats of V2c row), one f32 atomic per lane.
__global__ __launch_bounds__(256) void consume_kernel(
    const int* __restrict__ src, const int* __restrict__ dst,
    const float* __restrict__ vals, const float* __restrict__ V2c,
    float* __restrict__ out,
    int kBase, int edgeBase, int nEdgesChunk, int N, int E) {
    int t = blockIdx.x * blockDim.x + threadIdx.x;
    int el = t >> 4;
    int o = t & 15;
    if (el >= nEdgesChunk) return;
    int edge = edgeBase + el;

    int r = edge / E;
    int d = dst[edge];
    int s = src[edge];
    float v = vals[edge];

    int row = r * N + d - kBase;       // chunk-relative V2 row
    float m = v * V2c[(size_t)row * OUT_DIM + o];
    atomicAdd(out + (size_t)s * OUT_DIM + o, m);
}

__global__ __launch_bounds__(256) void relu_inplace_kernel(float4* __restrict__ p, int n4) {
    int i = blockIdx.x * blockDim.x + threadIdx.x;
    int stride = gridDim.x * blockDim.x;
    for (; i < n4; i += stride) {
        float4 v = p[i];
        v.x = fmaxf(v.x, 0.f); v.y = fmaxf(v.y, 0.f);
        v.z = fmaxf(v.z, 0.f); v.w = fmaxf(v.w, 0.f);
        p[i] = v;
    }
}

// ---------------- fallback (round-3 path, known 486us) ----------------
constexpr int NXCD = 8;
constexpr int EDGES_PER_BLOCK = 64;

__global__ __launch_bounds__(256) void rgcn_edge_atomic_kernel(
    const int* __restrict__ src, const int* __restrict__ dst,
    const float* __restrict__ vals, const float* __restrict__ W,
    const float* __restrict__ Wcomp, float* __restrict__ out,
    int N, int E, int nEdges, int chunksPerXcd, int nChunks) {
    __shared__ float wc[S_REL * B_BASES];
    for (int i = threadIdx.x; i < S_REL * B_BASES; i += blockDim.x) wc[i] = Wcomp[i];
    __syncthreads();
    const int x = blockIdx.x % NXCD;
    const int j = blockIdx.x / NXCD;
    const int chunk = x * chunksPerXcd + j;
    if (chunk >= nChunks) return;
    const int edge = chunk * EDGES_PER_BLOCK + (threadIdx.x >> 2);
    const int o4 = (threadIdx.x & 3) * 4;
    if (edge >= nEdges) return;
    const int r = edge / E;
    const int d = dst[edge];
    const int s = src[edge];
    const float v = vals[edge];
    const int k = r * N + d;
    const int node = k / S_REL;
    const int rel = k - node * S_REL;
    const float* wp = W + (size_t)node * OUT_DIM + o4;
    const size_t bstride = (size_t)N * OUT_DIM;
    const float* wcr = wc + rel * B_BASES;
    float4 acc = make_float4(0.f, 0.f, 0.f, 0.f);
#pragma unroll
    for (int b = 0; b < B_BASES; ++b) {
        float4 w4 = *reinterpret_cast<const float4*>(wp + (size_t)b * bstride);
        float c = wcr[b];
        acc.x = fmaf(c, w4.x, acc.x); acc.y = fmaf(c, w4.y, acc.y);
        acc.z = fmaf(c, w4.z, acc.z); acc.w = fmaf(c, w4.w, acc.w);
    }
    float* op = out + (size_t)s * OUT_DIM + o4;
    atomicAdd(op + 0, v * acc.x); atomicAdd(op + 1, v * acc.y);
    atomicAdd(op + 2, v * acc.z); atomicAdd(op + 3, v * acc.w);
}

extern "C" void kernel_launch(void* const* d_in, const int* in_sizes, int n_in,
                              void* d_out, int out_size, void* d_ws, size_t ws_size,
                              hipStream_t stream) {
    // setup_inputs order: features, src, dst, vals, W, W_comp
    const int* src = (const int*)d_in[1];
    const int* dst = (const int*)d_in[2];
    const float* vals = (const float*)d_in[3];
    const float* W = (const float*)d_in[4];
    const float* Wcomp = (const float*)d_in[5];
    float* out = (float*)d_out;

    const int N = in_sizes[0];            // 100000
    const int nEdges = in_sizes[1];       // S*E = 1M
    const int E = nEdges / S_REL;         // 20000

    hipMemsetAsync(d_out, 0, (size_t)out_size * sizeof(float), stream);

    // Per-relation V2 slab = N*16 floats = 6.4 MB. Chunk by Rc relations;
    // prefer 64MB chunks (L3-resident between build and consume).
    const size_t relBytes = (size_t)N * OUT_DIM * sizeof(float);
    int cap = (int)(ws_size / relBytes);
    int Rc = cap < 10 ? cap : 10;
    if (Rc > S_REL) Rc = S_REL;

    if (Rc < 1) {
        // ws too small: round-3 fallback
        const int nChunks = (nEdges + EDGES_PER_BLOCK - 1) / EDGES_PER_BLOCK;
        const int chunksPerXcd = (nChunks + NXCD - 1) / NXCD;
        rgcn_edge_atomic_kernel<<<chunksPerXcd * NXCD, 256, 0, stream>>>(
            src, dst, vals, W, Wcomp, out, N, E, nEdges, chunksPerXcd, nChunks);
    } else {
        float* V2c = (float*)d_ws;
        for (int r0 = 0; r0 < S_REL; r0 += Rc) {
            const int rc = (r0 + Rc <= S_REL) ? Rc : (S_REL - r0);
            const int rows = rc * N;
            const int kBase = r0 * N;
            const int edgeBase = r0 * E;
            const int nEdgesChunk = rc * E;

            const int bblocks = (rows * 4 + 255) / 256;
            build_v2_kernel<<<bblocks, 256, 0, stream>>>(W, Wcomp, V2c, kBase, rows, N);

            const int cblocks = (nEdgesChunk * 16 + 255) / 256;
            consume_kernel<<<cblocks, 256, 0, stream>>>(src, dst, vals, V2c, out,
                                                        kBase, edgeBase, nEdgesChunk, N, E);
        }
    }

    const int n4 = out_size / 4;
    int zb = (n4 + 255) / 256;
    relu_inplace_kernel<<<(zb < 2048 ? zb : 2048), 256, 0, stream>>>((float4*)out, n4);
}

// Round 10
// 586.646 us; speedup vs baseline: 1.3983x; 1.3983x over previous
//
#include <hip/hip_runtime.h>

// RGCN featureless: N=100000, S=50, B=30, OUT=16, E=20000 edges/rel.
// Reference: k = r*N + dst; V2 row k has node'=k/50, rel'=k%50;
// out[src] += val * V2[k][:]; ReLU.
//
// R2-R6 evidence: cost ≈ slow-transactions/edge (random 64B gather lines AND
// scalar f32 atomics each ~5-6cyc/CU). 16 atomics/edge alone = ~250us/1M edges
// (R6-consume), 30 gathers alone = ~273us (R4). This round: 1 gather line + 1
// int atomic + 1 coalesced line-write per edge; V2 built once, coalesced.
constexpr int S_REL = 50;
constexpr int B_BASES = 30;
constexpr int OUT_DIM = 16;
constexpr int TILE_N = 32;      // nodes per build block

// ---- build: V2[node*50+rel][0:16] = sum_b Wcomp[rel,b] * W[b][node][0:16] ----
// 128 threads = 32 nodes x 4 o4-quads. Thread t's 30 input float4s
// W4[b*N*4 + nodeBase*4 + t] are exactly the fragments it consumes and the
// wave's loads are fully coalesced (512B/instr) -> load straight to registers
// (R7's LDS staging was an identity round-trip; removed for occupancy).
__global__ __launch_bounds__(128) void build_v2_tiled(
    const float4* __restrict__ W4, const float* __restrict__ Wcomp,
    float4* __restrict__ V24, int N) {
    __shared__ float scw[S_REL * B_BASES];        // 6 KB
    const int t = threadIdx.x;
    const int nodeBase = blockIdx.x * TILE_N;
    const int nf4 = N * 4;

    for (int i = t; i < S_REL * B_BASES; i += 128) scw[i] = Wcomp[i];

    float4 f[B_BASES];
    const int off = nodeBase * 4 + t;
#pragma unroll
    for (int b = 0; b < B_BASES; ++b)
        f[b] = (off < nf4) ? W4[(size_t)b * nf4 + off]
                           : make_float4(0.f, 0.f, 0.f, 0.f);
    __syncthreads();

    const int nl = t >> 2;
    const int o4 = t & 3;
    const int node = nodeBase + nl;
    if (node >= N) return;

    for (int rel = 0; rel < S_REL; ++rel) {
        const float* c = &scw[rel * B_BASES];
        float4 a = make_float4(0.f, 0.f, 0.f, 0.f);
#pragma unroll
        for (int b = 0; b < B_BASES; ++b) {
            float cb = c[b];
            a.x = fmaf(cb, f[b].x, a.x);
            a.y = fmaf(cb, f[b].y, a.y);
            a.z = fmaf(cb, f[b].z, a.z);
            a.w = fmaf(cb, f[b].w, a.w);
        }
        V24[((size_t)node * S_REL + rel) * 4 + o4] = a;
    }
}

// ---- counting sort: hist -> two-level scan -> offsets & cursors ----
__global__ __launch_bounds__(256) void hist_kernel(
    const int* __restrict__ src, unsigned* __restrict__ cnt, int nEdges) {
    int i = blockIdx.x * blockDim.x + threadIdx.x;
    int stride = gridDim.x * blockDim.x;
    for (; i < nEdges; i += stride) atomicAdd(&cnt[src[i]], 1u);
}

__global__ __launch_bounds__(1024) void scanA_kernel(
    const unsigned* __restrict__ cnt, unsigned* __restrict__ offs,
    unsigned* __restrict__ bsum, int N) {
    __shared__ unsigned s[1024];
    const int t = threadIdx.x;
    const int i = blockIdx.x * 1024 + t;
    unsigned x = (i < N) ? cnt[i] : 0u;
    s[t] = x;
    __syncthreads();
    for (int d = 1; d < 1024; d <<= 1) {
        unsigned v = (t >= d) ? s[t - d] : 0u;
        __syncthreads();
        s[t] += v;
        __syncthreads();
    }
    if (i < N) offs[i] = s[t] - x;           // exclusive within block
    if (t == 1023) bsum[blockIdx.x] = s[1023];
}

__global__ __launch_bounds__(64) void scanB_kernel(
    unsigned* __restrict__ bsum, unsigned* __restrict__ bofs, int nb) {
    if (threadIdx.x == 0) {
        unsigned run = 0;
        for (int j = 0; j < nb; ++j) { unsigned x = bsum[j]; bofs[j] = run; run += x; }
    }
}

__global__ __launch_bounds__(1024) void scanC_kernel(
    unsigned* __restrict__ offs, unsigned* __restrict__ cur,
    const unsigned* __restrict__ bofs, int N, int nEdges) {
    const int i = blockIdx.x * 1024 + threadIdx.x;
    if (i < N) {
        unsigned o = offs[i] + bofs[i >> 10];
        offs[i] = o;
        cur[i] = o;
    }
    if (i == 0) offs[N] = (unsigned)nEdges;
}

// ---- consume: 4 lanes/edge; 1 gather line + 1 cursor atomic + 1 line store ----
__global__ __launch_bounds__(256) void consume_kernel(
    const int* __restrict__ src, const int* __restrict__ dst,
    const float* __restrict__ vals, const float4* __restrict__ V24,
    float4* __restrict__ M4, unsigned* __restrict__ cur,
    int N, int E, int nEdges) {
    int t = blockIdx.x * blockDim.x + threadIdx.x;
    int e = t >> 2;
    int q = t & 3;
    if (e >= nEdges) return;
    int r = e / E;
    int d = dst[e];
    int s = src[e];
    float v = vals[e];
    int k = r * N + d;
    float4 g = V24[(size_t)k * 4 + q];
    float4 m = make_float4(v * g.x, v * g.y, v * g.z, v * g.w);
    unsigned pos = 0;
    if (q == 0) pos = atomicAdd(&cur[s], 1u);
    pos = __shfl(pos, 0, 4);
    M4[(size_t)pos * 4 + q] = m;
}

// ---- reduce: 4 lanes/node, sum contiguous segment, ReLU, store all nodes ----
__global__ __launch_bounds__(256) void reduce_kernel(
    const float4* __restrict__ M4, const unsigned* __restrict__ offs,
    float4* __restrict__ out4, int N) {
    int t = blockIdx.x * blockDim.x + threadIdx.x;
    int n = t >> 2;
    int q = t & 3;
    if (n >= N) return;
    unsigned b = offs[n];
    unsigned e = offs[n + 1];
    float4 a = make_float4(0.f, 0.f, 0.f, 0.f);
    for (unsigned p = b; p < e; ++p) {
        float4 m = M4[(size_t)p * 4 + q];
        a.x += m.x; a.y += m.y; a.z += m.z; a.w += m.w;
    }
    out4[(size_t)n * 4 + q] = make_float4(fmaxf(a.x, 0.f), fmaxf(a.y, 0.f),
                                          fmaxf(a.z, 0.f), fmaxf(a.w, 0.f));
}

// ---- fallback (round-3 path, known-good 486us) ----
constexpr int NXCD = 8;
constexpr int EDGES_PER_BLOCK = 64;

__global__ __launch_bounds__(256) void relu_inplace_kernel(float4* __restrict__ p, int n4) {
    int i = blockIdx.x * blockDim.x + threadIdx.x;
    int stride = gridDim.x * blockDim.x;
    for (; i < n4; i += stride) {
        float4 v = p[i];
        v.x = fmaxf(v.x, 0.f); v.y = fmaxf(v.y, 0.f);
        v.z = fmaxf(v.z, 0.f); v.w = fmaxf(v.w, 0.f);
        p[i] = v;
    }
}

__global__ __launch_bounds__(256) void rgcn_edge_atomic_kernel(
    const int* __restrict__ src, const int* __restrict__ dst,
    const float* __restrict__ vals, const float* __restrict__ W,
    const float* __restrict__ Wcomp, float* __restrict__ out,
    int N, int E, int nEdges, int chunksPerXcd, int nChunks) {
    __shared__ float wc[S_REL * B_BASES];
    for (int i = threadIdx.x; i < S_REL * B_BASES; i += blockDim.x) wc[i] = Wcomp[i];
    __syncthreads();
    const int x = blockIdx.x % NXCD;
    const int j = blockIdx.x / NXCD;
    const int chunk = x * chunksPerXcd + j;
    if (chunk >= nChunks) return;
    const int edge = chunk * EDGES_PER_BLOCK + (threadIdx.x >> 2);
    const int o4 = (threadIdx.x & 3) * 4;
    if (edge >= nEdges) return;
    const int r = edge / E;
    const int d = dst[edge];
    const int s = src[edge];
    const float v = vals[edge];
    const int k = r * N + d;
    const int node = k / S_REL;
    const int rel = k - node * S_REL;
    const float* wp = W + (size_t)node * OUT_DIM + o4;
    const size_t bstride = (size_t)N * OUT_DIM;
    const float* wcr = wc + rel * B_BASES;
    float4 acc = make_float4(0.f, 0.f, 0.f, 0.f);
#pragma unroll
    for (int b = 0; b < B_BASES; ++b) {
        float4 w4 = *reinterpret_cast<const float4*>(wp + (size_t)b * bstride);
        float c = wcr[b];
        acc.x = fmaf(c, w4.x, acc.x); acc.y = fmaf(c, w4.y, acc.y);
        acc.z = fmaf(c, w4.z, acc.z); acc.w = fmaf(c, w4.w, acc.w);
    }
    float* op = out + (size_t)s * OUT_DIM + o4;
    atomicAdd(op + 0, v * acc.x); atomicAdd(op + 1, v * acc.y);
    atomicAdd(op + 2, v * acc.z); atomicAdd(op + 3, v * acc.w);
}

extern "C" void kernel_launch(void* const* d_in, const int* in_sizes, int n_in,
                              void* d_out, int out_size, void* d_ws, size_t ws_size,
                              hipStream_t stream) {
    // setup_inputs order: features, src, dst, vals, W, W_comp
    const int* src = (const int*)d_in[1];
    const int* dst = (const int*)d_in[2];
    const float* vals = (const float*)d_in[3];
    const float* W = (const float*)d_in[4];
    const float* Wcomp = (const float*)d_in[5];

    const int N = in_sizes[0];            // 100000
    const int nEdges = in_sizes[1];       // 1M
    const int E = nEdges / S_REL;         // 20000

    // ws layout: V2 (S*N*16 f32) | msgs (nEdges*16 f32) | cnt | offs(N+1) | cur | bsum | bofs
    const int nbScan = (N + 1023) / 1024;
    const size_t v2Bytes = (size_t)S_REL * N * OUT_DIM * sizeof(float);
    const size_t msgBytes = (size_t)nEdges * OUT_DIM * sizeof(float);
    const size_t intBytes = ((size_t)3 * N + 1 + 2 * nbScan) * sizeof(unsigned);
    const size_t needed = v2Bytes + msgBytes + intBytes;

    if (ws_size < needed) {
        // fallback: round-3 atomic path
        float* out = (float*)d_out;
        hipMemsetAsync(d_out, 0, (size_t)out_size * sizeof(float), stream);
        const int nChunks = (nEdges + EDGES_PER_BLOCK - 1) / EDGES_PER_BLOCK;
        const int chunksPerXcd = (nChunks + NXCD - 1) / NXCD;
        rgcn_edge_atomic_kernel<<<chunksPerXcd * NXCD, 256, 0, stream>>>(
            src, dst, vals, W, Wcomp, out, N, E, nEdges, chunksPerXcd, nChunks);
        const int n4 = out_size / 4;
        int zb = (n4 + 255) / 256;
        relu_inplace_kernel<<<(zb < 2048 ? zb : 2048), 256, 0, stream>>>((float4*)out, n4);
        return;
    }

    float4* V24 = (float4*)d_ws;
    float4* M4 = (float4*)((char*)d_ws + v2Bytes);
    unsigned* cnt = (unsigned*)((char*)d_ws + v2Bytes + msgBytes);
    unsigned* offs = cnt + N;
    unsigned* cur = offs + N + 1;
    unsigned* bsum = cur + N;
    unsigned* bofs = bsum + nbScan;

    // build whole V2 (one dispatch, fully coalesced, fma-bound)
    const int bblocks = (N + TILE_N - 1) / TILE_N;
    build_v2_tiled<<<bblocks, 128, 0, stream>>>((const float4*)W, Wcomp, V24, N);

    // counting sort of edges by src
    hipMemsetAsync(cnt, 0, (size_t)N * sizeof(unsigned), stream);
    int hb = (nEdges + 255) / 256;
    hist_kernel<<<(hb < 2048 ? hb : 2048), 256, 0, stream>>>(src, cnt, nEdges);
    scanA_kernel<<<nbScan, 1024, 0, stream>>>(cnt, offs, bsum, N);
    scanB_kernel<<<1, 64, 0, stream>>>(bsum, bofs, nbScan);
    scanC_kernel<<<nbScan, 1024, 0, stream>>>(offs, cur, bofs, N, nEdges);

    // gather + sorted message write (1 line + 1 int atomic per edge)
    const long long cthreads = (long long)nEdges * 4;
    consume_kernel<<<(int)((cthreads + 255) / 256), 256, 0, stream>>>(
        src, dst, vals, V24, M4, cur, N, E, nEdges);

    // segment reduce + ReLU (writes every node; no zero-init pass needed)
    const int rblocks = (N * 4 + 255) / 256;
    reduce_kernel<<<rblocks, 256, 0, stream>>>(M4, offs, (float4*)d_out, N);
}

// Round 11
// 584.038 us; speedup vs baseline: 1.4046x; 1.0045x over previous
//
#include <hip/hip_runtime.h>

// RGCN featureless: N=100000, S=50, B=30, OUT=16, E=20000 edges/rel.
// k = r*N + dst; node' = k/50; rel' = k%50 = dst%50 (N%50==0);
// out[src] += val * sum_b Wcomp[rel',b] * W[b][node'][:]; ReLU.
//
// R10 evidence: V2 build = 256us (VGPR 136 -> occ 10%, latency-bound), V2
// 320MB write for 64MB of gathered rows. R3 evidence: 30 random gather
// lines/edge = 278us at 88% occ. This round: counting-sort edges by node'
// so a wave's 16 edges share node' -> 30 gathers become L1-resident
// (~1-2 lines/instr, W streams once); output via src-sorted msg scatter
// (1 int atomic + 1 64B line/edge) + segment reduce. No V2, no f32 atomics.
constexpr int S_REL = 50;
constexpr int B_BASES = 30;
constexpr int OUT_DIM = 16;
constexpr int NXCD = 8;
constexpr int EDGES_PER_BLOCK = 64;   // edge pass: 256 thr, 4 lanes/edge

// ---- hist both keys: node' bins and src bins ----
__global__ __launch_bounds__(256) void hist2_kernel(
    const int* __restrict__ src, const int* __restrict__ dst,
    unsigned* __restrict__ cntNode, unsigned* __restrict__ cntSrc,
    int N, int E, int nEdges) {
    int i = blockIdx.x * blockDim.x + threadIdx.x;
    int stride = gridDim.x * blockDim.x;
    for (; i < nEdges; i += stride) {
        int r = i / E;
        int node = (r * N + dst[i]) / S_REL;
        atomicAdd(&cntNode[node], 1u);
        atomicAdd(&cntSrc[src[i]], 1u);
    }
}

// ---- two-level exclusive scan (as R8, proven machinery) ----
__global__ __launch_bounds__(1024) void scanA_kernel(
    const unsigned* __restrict__ cnt, unsigned* __restrict__ offs,
    unsigned* __restrict__ bsum, int NB) {
    __shared__ unsigned s[1024];
    const int t = threadIdx.x;
    const int i = blockIdx.x * 1024 + t;
    unsigned x = (i < NB) ? cnt[i] : 0u;
    s[t] = x;
    __syncthreads();
    for (int d = 1; d < 1024; d <<= 1) {
        unsigned v = (t >= d) ? s[t - d] : 0u;
        __syncthreads();
        s[t] += v;
        __syncthreads();
    }
    if (i < NB) offs[i] = s[t] - x;
    if (t == 1023) bsum[blockIdx.x] = s[1023];
}

__global__ __launch_bounds__(64) void scanB_kernel(
    unsigned* __restrict__ bsum, unsigned* __restrict__ bofs, int nb) {
    if (threadIdx.x == 0) {
        unsigned run = 0;
        for (int j = 0; j < nb; ++j) { unsigned x = bsum[j]; bofs[j] = run; run += x; }
    }
}

__global__ __launch_bounds__(1024) void scanC_kernel(
    unsigned* __restrict__ offs, unsigned* __restrict__ cur,
    const unsigned* __restrict__ bofs, int NB, int total) {
    const int i = blockIdx.x * 1024 + threadIdx.x;
    if (i < NB) {
        unsigned o = offs[i] + bofs[i >> 10];
        offs[i] = o;
        cur[i] = o;
    }
    if (i == 0) offs[NB] = (unsigned)total;
}

// ---- scatter payload sorted by node': (src, d%50, val, node') 16B/edge ----
__global__ __launch_bounds__(256) void scatter_kernel(
    const int* __restrict__ src, const int* __restrict__ dst,
    const float* __restrict__ vals, float4* __restrict__ pay,
    unsigned* __restrict__ curNode, int N, int E, int nEdges) {
    int i = blockIdx.x * blockDim.x + threadIdx.x;
    int stride = gridDim.x * blockDim.x;
    for (; i < nEdges; i += stride) {
        int r = i / E;
        int d = dst[i];
        int k = r * N + d;
        int node = k / S_REL;                 // const divisor -> magic mul
        int dmod = k - node * S_REL;          // == d % 50
        unsigned pos = atomicAdd(&curNode[node], 1u);
        pay[pos] = make_float4(__int_as_float(src[i]), __int_as_float(dmod),
                               vals[i], __int_as_float(node));
    }
}

// ---- edge pass over node'-sorted payload: 4 lanes/edge ----
// Wave's 16 edges share node' (avg ~10 edges/bin) -> the 30 gather instrs
// touch 1-2 distinct 64B lines each, L1-resident; W streams once in order.
// Output: 1 cursor atomic + one 64B msg line into src-sorted M.
__global__ __launch_bounds__(256) void edge_sorted_kernel(
    const float4* __restrict__ pay, const float4* __restrict__ W4,
    const float* __restrict__ Wcomp, float4* __restrict__ M4,
    unsigned* __restrict__ curSrc, int N, int nEdges,
    int chunksPerXcd, int nChunks) {
    __shared__ float scw[S_REL * B_BASES];    // 6 KB
    for (int i = threadIdx.x; i < S_REL * B_BASES; i += blockDim.x)
        scw[i] = Wcomp[i];
    __syncthreads();

    const int x = blockIdx.x % NXCD;          // XCD-chunked: each L2 streams
    const int j = blockIdx.x / NXCD;          // a contiguous sorted range
    const int chunk = x * chunksPerXcd + j;
    if (chunk >= nChunks) return;
    const int e = chunk * EDGES_PER_BLOCK + (threadIdx.x >> 2);
    const int q = threadIdx.x & 3;
    if (e >= nEdges) return;

    float4 p = pay[e];
    const int s = __float_as_int(p.x);
    const int dmod = __float_as_int(p.y);
    const float v = p.z;
    const int node = __float_as_int(p.w);

    const float4* wp = W4 + (size_t)node * 4 + q;
    const size_t bstride = (size_t)N * 4;     // float4s between bases
    const float* c = &scw[dmod * B_BASES];

    float4 a = make_float4(0.f, 0.f, 0.f, 0.f);
#pragma unroll
    for (int b = 0; b < B_BASES; ++b) {
        float4 w = wp[(size_t)b * bstride];
        float cb = c[b];
        a.x = fmaf(cb, w.x, a.x);
        a.y = fmaf(cb, w.y, a.y);
        a.z = fmaf(cb, w.z, a.z);
        a.w = fmaf(cb, w.w, a.w);
    }

    unsigned pos = 0;
    if (q == 0) pos = atomicAdd(&curSrc[s], 1u);
    pos = __shfl(pos, 0, 4);
    M4[(size_t)pos * 4 + q] = make_float4(v * a.x, v * a.y, v * a.z, v * a.w);
}

// ---- reduce by src segment + ReLU; writes every node (no zero-init) ----
__global__ __launch_bounds__(256) void reduce_kernel(
    const float4* __restrict__ M4, const unsigned* __restrict__ offs,
    float4* __restrict__ out4, int N) {
    int t = blockIdx.x * blockDim.x + threadIdx.x;
    int n = t >> 2;
    int q = t & 3;
    if (n >= N) return;
    unsigned b = offs[n];
    unsigned e = offs[n + 1];
    float4 a = make_float4(0.f, 0.f, 0.f, 0.f);
    for (unsigned p = b; p < e; ++p) {
        float4 m = M4[(size_t)p * 4 + q];
        a.x += m.x; a.y += m.y; a.z += m.z; a.w += m.w;
    }
    out4[(size_t)n * 4 + q] = make_float4(fmaxf(a.x, 0.f), fmaxf(a.y, 0.f),
                                          fmaxf(a.z, 0.f), fmaxf(a.w, 0.f));
}

// ---- fallback (round-3 path, known-good 486us) ----
__global__ __launch_bounds__(256) void relu_inplace_kernel(float4* __restrict__ p, int n4) {
    int i = blockIdx.x * blockDim.x + threadIdx.x;
    int stride = gridDim.x * blockDim.x;
    for (; i < n4; i += stride) {
        float4 v = p[i];
        v.x = fmaxf(v.x, 0.f); v.y = fmaxf(v.y, 0.f);
        v.z = fmaxf(v.z, 0.f); v.w = fmaxf(v.w, 0.f);
        p[i] = v;
    }
}

__global__ __launch_bounds__(256) void rgcn_edge_atomic_kernel(
    const int* __restrict__ src, const int* __restrict__ dst,
    const float* __restrict__ vals, const float* __restrict__ W,
    const float* __restrict__ Wcomp, float* __restrict__ out,
    int N, int E, int nEdges, int chunksPerXcd, int nChunks) {
    __shared__ float wc[S_REL * B_BASES];
    for (int i = threadIdx.x; i < S_REL * B_BASES; i += blockDim.x) wc[i] = Wcomp[i];
    __syncthreads();
    const int x = blockIdx.x % NXCD;
    const int j = blockIdx.x / NXCD;
    const int chunk = x * chunksPerXcd + j;
    if (chunk >= nChunks) return;
    const int edge = chunk * EDGES_PER_BLOCK + (threadIdx.x >> 2);
    const int o4 = (threadIdx.x & 3) * 4;
    if (edge >= nEdges) return;
    const int r = edge / E;
    const int d = dst[edge];
    const int s = src[edge];
    const float v = vals[edge];
    const int k = r * N + d;
    const int node = k / S_REL;
    const int rel = k - node * S_REL;
    const float* wp = W + (size_t)node * OUT_DIM + o4;
    const size_t bstride = (size_t)N * OUT_DIM;
    const float* wcr = wc + rel * B_BASES;
    float4 acc = make_float4(0.f, 0.f, 0.f, 0.f);
#pragma unroll
    for (int b = 0; b < B_BASES; ++b) {
        float4 w4 = *reinterpret_cast<const float4*>(wp + (size_t)b * bstride);
        float c = wcr[b];
        acc.x = fmaf(c, w4.x, acc.x); acc.y = fmaf(c, w4.y, acc.y);
        acc.z = fmaf(c, w4.z, acc.z); acc.w = fmaf(c, w4.w, acc.w);
    }
    float* op = out + (size_t)s * OUT_DIM + o4;
    atomicAdd(op + 0, v * acc.x); atomicAdd(op + 1, v * acc.y);
    atomicAdd(op + 2, v * acc.z); atomicAdd(op + 3, v * acc.w);
}

extern "C" void kernel_launch(void* const* d_in, const int* in_sizes, int n_in,
                              void* d_out, int out_size, void* d_ws, size_t ws_size,
                              hipStream_t stream) {
    // setup_inputs order: features, src, dst, vals, W, W_comp
    const int* src = (const int*)d_in[1];
    const int* dst = (const int*)d_in[2];
    const float* vals = (const float*)d_in[3];
    const float* W = (const float*)d_in[4];
    const float* Wcomp = (const float*)d_in[5];

    const int N = in_sizes[0];            // 100000
    const int nEdges = in_sizes[1];       // 1M
    const int E = nEdges / S_REL;         // 20000

    // ws: pay (nEdges f4) | M (nEdges*4 f4) | cnt1 cnt2 (2N) | offs1(N+1)
    //     cur1(N) | offs2(N+1) cur2(N) | bsum bofs (2*nb)
    const int nb = (N + 1023) / 1024;
    const size_t payBytes = (size_t)nEdges * sizeof(float4);
    const size_t mBytes = (size_t)nEdges * OUT_DIM * sizeof(float);
    const size_t uints = (size_t)6 * N + 2 + 2 * nb;
    const size_t needed = payBytes + mBytes + uints * sizeof(unsigned);

    const int nChunks = (nEdges + EDGES_PER_BLOCK - 1) / EDGES_PER_BLOCK;
    const int chunksPerXcd = (nChunks + NXCD - 1) / NXCD;
    const int eblocks = chunksPerXcd * NXCD;

    if (ws_size < needed) {
        // fallback: round-3 atomic path (known 486us)
        float* out = (float*)d_out;
        hipMemsetAsync(d_out, 0, (size_t)out_size * sizeof(float), stream);
        rgcn_edge_atomic_kernel<<<eblocks, 256, 0, stream>>>(
            src, dst, vals, W, Wcomp, out, N, E, nEdges, chunksPerXcd, nChunks);
        const int n4 = out_size / 4;
        int zb = (n4 + 255) / 256;
        relu_inplace_kernel<<<(zb < 2048 ? zb : 2048), 256, 0, stream>>>((float4*)out, n4);
        return;
    }

    float4* pay = (float4*)d_ws;
    float4* M4 = (float4*)((char*)d_ws + payBytes);
    unsigned* cnt1 = (unsigned*)((char*)d_ws + payBytes + mBytes);
    unsigned* cnt2 = cnt1 + N;
    unsigned* offs1 = cnt2 + N;           // N+1 (unused after scan; kept simple)
    unsigned* cur1 = offs1 + N + 1;
    unsigned* offs2 = cur1 + N;           // N+1
    unsigned* cur2 = offs2 + N + 1;
    unsigned* bsum = cur2 + N;
    unsigned* bofs = bsum + nb;

    hipMemsetAsync(cnt1, 0, (size_t)2 * N * sizeof(unsigned), stream);  // cnt1+cnt2

    int gb = (nEdges + 255) / 256;
    if (gb > 2048) gb = 2048;
    hist2_kernel<<<gb, 256, 0, stream>>>(src, dst, cnt1, cnt2, N, E, nEdges);

    // scan node' bins -> cur1
    scanA_kernel<<<nb, 1024, 0, stream>>>(cnt1, offs1, bsum, N);
    scanB_kernel<<<1, 64, 0, stream>>>(bsum, bofs, nb);
    scanC_kernel<<<nb, 1024, 0, stream>>>(offs1, cur1, bofs, N, nEdges);

    // scatter payload into node'-sorted order
    scatter_kernel<<<gb, 256, 0, stream>>>(src, dst, vals, pay, cur1, N, E, nEdges);

    // scan src bins -> offs2, cur2
    scanA_kernel<<<nb, 1024, 0, stream>>>(cnt2, offs2, bsum, N);
    scanB_kernel<<<1, 64, 0, stream>>>(bsum, bofs, nb);
    scanC_kernel<<<nb, 1024, 0, stream>>>(offs2, cur2, bofs, N, nEdges);

    // main edge pass: sorted gathers + src-sorted msg scatter
    edge_sorted_kernel<<<eblocks, 256, 0, stream>>>(
        pay, (const float4*)W, Wcomp, M4, cur2, N, nEdges, chunksPerXcd, nChunks);

    // segment reduce + ReLU
    const int rblocks = (N * 4 + 255) / 256;
    reduce_kernel<<<rblocks, 256, 0, stream>>>(M4, offs2, (float4*)d_out, N);
}